// Round 7
// baseline (615.945 us; speedup 1.0000x reference)
//
#include <hip/hip_runtime.h>
#include <hip/hip_bf16.h>
#include <math.h>

#define NTOK 4096
#define DD 1024
#define FF 4096
#define NE 8
#define KSEL 2
#define BK 64
#define PADR 256
#define ROWCAP 10240   // 40 tiles * 256; covers worst-case 256-padding (8192+2040)
#define MT 40

typedef __attribute__((ext_vector_type(8))) short short8_t;
typedef __attribute__((ext_vector_type(4))) float f32x4;

__device__ __forceinline__ unsigned short f2bf(float f){
  unsigned u = __float_as_uint(f);
  return (unsigned short)((u + 0x7fffu + ((u >> 16) & 1u)) >> 16);
}

// bijective XCD-chunked swizzle (m204)
__device__ __forceinline__ int xcd_swz(int lin, int nwg){
  int q = nwg >> 3, r = nwg & 7;
  int xcd = lin & 7, idx = lin >> 3;
  return (xcd < r ? xcd * (q + 1) : r * (q + 1) + (xcd - r) * q) + idx;
}

#define GLOAD_LDS(g, l) \
  __builtin_amdgcn_global_load_lds((const __attribute__((address_space(1))) void*)(g), \
                                   (__attribute__((address_space(3))) void*)(l), 16, 0, 0)
#define WAIT_VL asm volatile("s_waitcnt vmcnt(0) lgkmcnt(0)" ::: "memory")
#define WAIT_V  asm volatile("s_waitcnt vmcnt(0)" ::: "memory")
#define RAWBAR __builtin_amdgcn_s_barrier()
#define PRIO1 __builtin_amdgcn_s_setprio(1)
#define PRIO0 __builtin_amdgcn_s_setprio(0)

// ---------------- gating (top2 + weights) ----------------

__global__ void k_prep(const float* __restrict__ x, const float* __restrict__ wg,
                       int* __restrict__ topk_idx, float* __restrict__ topk_gate,
                       int* __restrict__ counts){
  int wid = threadIdx.x >> 6, lane = threadIdx.x & 63;
  int t = blockIdx.x * 4 + wid;
  const float* xr = x + (size_t)t * DD;
  double acc[NE];
#pragma unroll
  for (int e = 0; e < NE; ++e) acc[e] = 0.0;
#pragma unroll
  for (int p = 0; p < 4; ++p){
    int d = p * 256 + lane * 4;
    float4 v = *(const float4*)(xr + d);
    const float* w0 = wg + (size_t)d * NE;
    float vv[4] = {v.x, v.y, v.z, v.w};
#pragma unroll
    for (int j = 0; j < 4; ++j){
      double xv = (double)vv[j];
#pragma unroll
      for (int e = 0; e < NE; ++e) acc[e] += xv * (double)w0[j * NE + e];
    }
  }
#pragma unroll
  for (int e = 0; e < NE; ++e){
#pragma unroll
    for (int s = 32; s; s >>= 1) acc[e] += __shfl_xor(acc[e], s, 64);
  }
  if (lane == 0){
    int i0 = 0; double v0 = acc[0];
#pragma unroll
    for (int e = 1; e < NE; ++e) if (acc[e] > v0){ v0 = acc[e]; i0 = e; }
    int i1 = -1; double v1 = -1e300;
#pragma unroll
    for (int e = 0; e < NE; ++e) if (e != i0 && acc[e] > v1){ v1 = acc[e]; i1 = e; }
    double g0 = 1.0 / (1.0 + exp(v1 - v0));
    topk_idx[2 * t] = i0; topk_idx[2 * t + 1] = i1;
    topk_gate[2 * t] = (float)g0; topk_gate[2 * t + 1] = (float)(1.0 - g0);
    atomicAdd(&counts[i0], 1);
    atomicAdd(&counts[i1], 1);
  }
}

// ---------------- fused weight transpose+convert ----------------
// W1 [E][D][F] -> w1t [E][F][D];  W2 [E][F][D] -> w2t [E][D][F]

__global__ void k_transpose_all(const float* __restrict__ W1, const float* __restrict__ W2,
                                short* __restrict__ w1t, short* __restrict__ w2t){
  __shared__ short T[64][132];
  int id = blockIdx.x;
  bool isW2 = id >= 4096;
  int rem = id & 4095;
  int e = rem >> 9;
  int tr = rem & 511;
  int R, C, c0, r0;
  const float* in; short* out;
  if (!isW2){ R = DD; C = FF; c0 = (tr & 63) * 64; r0 = (tr >> 6) * 128;
              in = W1 + (size_t)e * R * C; out = w1t + (size_t)e * R * C; }
  else      { R = FF; C = DD; c0 = (tr & 15) * 64; r0 = (tr >> 4) * 128;
              in = W2 + (size_t)e * R * C; out = w2t + (size_t)e * R * C; }
  int t = threadIdx.x;
  int rr = t >> 4, c4 = (t & 15) * 4;
#pragma unroll
  for (int p = 0; p < 8; ++p){
    int row = p * 16 + rr;
    float4 v = *(const float4*)(in + (size_t)(r0 + row) * C + c0 + c4);
    T[c4 + 0][row] = (short)f2bf(v.x);
    T[c4 + 1][row] = (short)f2bf(v.y);
    T[c4 + 2][row] = (short)f2bf(v.z);
    T[c4 + 3][row] = (short)f2bf(v.w);
  }
  __syncthreads();
  int c8 = (t & 15) * 8;
#pragma unroll
  for (int q = 0; q < 4; ++q){
    int orow = q * 16 + rr;
    short4 lo = *(const short4*)&T[orow][c8];
    short4 hi = *(const short4*)&T[orow][c8 + 4];
    short8_t w;
    w[0] = lo.x; w[1] = lo.y; w[2] = lo.z; w[3] = lo.w;
    w[4] = hi.x; w[5] = hi.y; w[6] = hi.z; w[7] = hi.w;
    *(short8_t*)(out + (size_t)(c0 + orow) * R + r0 + c8) = w;
  }
}

// ---------------- routing (single block): pad-256 scan + slot assign ----------------

__global__ void k_route_all(const int* __restrict__ counts, const int* __restrict__ topk_idx,
                            const float* __restrict__ topk_gate, int* __restrict__ poff_g,
                            int* __restrict__ row_token, int* __restrict__ slot_of){
  __shared__ int poff[NE + 1], cur[NE], rends[NE];
  if (threadIdx.x == 0){
    int off = 0;
    for (int e = 0; e < NE; ++e){
      poff[e] = off; cur[e] = off; rends[e] = off + counts[e];
      off += (counts[e] + PADR - 1) & ~(PADR - 1);
    }
    poff[NE] = off;
    for (int e = 0; e <= NE; ++e) poff_g[e] = poff[e];
  }
  __syncthreads();
  for (int t = threadIdx.x; t < NTOK; t += 256){
#pragma unroll
    for (int k = 0; k < KSEL; ++k){
      int e = topk_idx[2 * t + k];
      int slot = atomicAdd(&cur[e], 1);
      row_token[slot] = t;
      slot_of[2 * t + k] = slot;
    }
  }
  __syncthreads();
#pragma unroll
  for (int e = 0; e < NE; ++e)
    for (int s = rends[e] + (int)threadIdx.x; s < poff[e + 1]; s += 256)
      row_token[s] = 0;
}

// ---------------- GEMM1: h = gelu(Xgather @ W1[e] + b1[e]) ----------------
// 256x256 tile, 8 waves (2Mx4N), 4-phase K-loop. A reg-staged from f32 x
// (issue-early ph0/1, cvt+ds_write ph2/3); B via global_load_lds.

__launch_bounds__(512, 2)
__global__ void k_gemm1(const float* __restrict__ x, const short* __restrict__ w1t,
                        const float* __restrict__ b1, short* __restrict__ h,
                        const int* __restrict__ row_token, const int* __restrict__ poff){
  __shared__ short As[2][2][8192];   // [buf][Mhalf][128*64]
  __shared__ short Bs[2][2][8192];   // [buf][Nhalf][128*64]
  int lin = xcd_swz(blockIdx.x, MT * (FF / 256));
  int by = lin / MT, bx = lin % MT;   // XCD chunk = 2 by x 40 bx -> shared B panel
  int row0 = bx * 256;
  if (row0 >= poff[NE]) return;
  int e = 0;
  while (row0 >= poff[e + 1]) ++e;
  int n0 = by * 256;
  int tid = threadIdx.x;
  int wid = tid >> 6, lane = tid & 63;
  int wr = wid >> 2, wc = wid & 3;
  int lrow = lane & 15, lk = lane >> 4;

  const short* bsrc[2];
#pragma unroll
  for (int p = 0; p < 2; ++p){
    int L = p * 512 + tid;
    int r = L >> 3, cd = (L & 7) ^ (r & 7);
    bsrc[p] = w1t + (size_t)e * FF * DD + (size_t)(n0 + r) * DD + cd * 8;
  }
  const float* asrc[2][4];
  int aelem[4];
#pragma unroll
  for (int p = 0; p < 4; ++p){
    int q = p * 512 + tid;
    int r = q >> 4, c4 = (q & 15) * 4;
    aelem[p] = r * 64 + (((c4 >> 3) ^ (r & 7)) << 3) + (c4 & 7);
#pragma unroll
    for (int h2 = 0; h2 < 2; ++h2){
      int tok = row_token[row0 + h2 * 128 + r];
      asrc[h2][p] = x + (size_t)tok * DD + c4;
    }
  }

  f32x4 acc[8][4];
#pragma unroll
  for (int i = 0; i < 8; ++i)
#pragma unroll
    for (int j = 0; j < 4; ++j) acc[i][j] = (f32x4){0.f, 0.f, 0.f, 0.f};

  auto rdA = [&](const short* A0, int mq, int kk, short8_t* av){
#pragma unroll
    for (int m = 0; m < 4; ++m){
      int r = mq * 64 + m * 16 + lrow;
      av[m] = *(const short8_t*)(A0 + r * 64 + (((kk * 4 + lk) ^ (r & 7)) << 3));
    }
  };
  auto rdB = [&](const short* B0, int kk, short8_t* bv){
#pragma unroll
    for (int n = 0; n < 4; ++n){
      int r = (wc & 1) * 64 + n * 16 + lrow;
      bv[n] = *(const short8_t*)(B0 + r * 64 + (((kk * 4 + lk) ^ (r & 7)) << 3));
    }
  };
  auto MF = [&](int mq, short8_t* av, short8_t* bv){
#pragma unroll
    for (int m = 0; m < 4; ++m)
#pragma unroll
      for (int n = 0; n < 4; ++n)
        acc[mq * 4 + m][n] = __builtin_amdgcn_mfma_f32_16x16x32_bf16(av[m], bv[n], acc[mq * 4 + m][n], 0, 0, 0);
  };
  auto aload = [&](float4* f, int h2, int k0){
#pragma unroll
    for (int p = 0; p < 4; ++p) f[p] = *(const float4*)(asrc[h2][p] + k0);
  };
  auto awrite = [&](float4* f, int nb, int h2){
    short* dst = &As[nb][h2][0];
#pragma unroll
    for (int p = 0; p < 4; ++p){
      short4 cv;
      cv.x = (short)f2bf(f[p].x); cv.y = (short)f2bf(f[p].y);
      cv.z = (short)f2bf(f[p].z); cv.w = (short)f2bf(f[p].w);
      *(short4*)(dst + aelem[p]) = cv;
    }
  };
  auto bstage = [&](int nb, int h2, int k0){
    GLOAD_LDS(bsrc[0] + (size_t)h2 * 128 * DD + k0, &Bs[nb][h2][0] + tid * 8);
    GLOAD_LDS(bsrc[1] + (size_t)h2 * 128 * DD + k0, &Bs[nb][h2][0] + 4096 + tid * 8);
  };

  float4 fa[4], fc[4];
  // prologue: tile 0 -> buf0
  aload(fa, 0, 0); aload(fc, 1, 0);
  bstage(0, 0, 0); bstage(0, 1, 0);
  awrite(fa, 0, 0); awrite(fc, 0, 1);
  WAIT_VL; RAWBAR;

#pragma unroll 1
  for (int kt = 0; kt < DD / BK; ++kt){
    int buf = kt & 1, nb = buf ^ 1;
    int k1 = (kt + 1) * BK;
    bool more = (kt + 1 < DD / BK);
    const short* A0 = &As[buf][wr][0];
    const short* B0 = &Bs[buf][wc >> 1][0];
    short8_t av[4], bv[4];
    // ph0: issue A-half0 f32 loads + stage B-half0(next)
    if (more){ aload(fa, 0, k1); bstage(nb, 0, k1); }
    rdB(B0, 0, bv); rdA(A0, 0, 0, av);
    RAWBAR; PRIO1; MF(0, av, bv); PRIO0; RAWBAR;
    // ph1: issue A-half1 loads + stage B-half1(next)
    if (more){ aload(fc, 1, k1); bstage(nb, 1, k1); }
    rdA(A0, 1, 0, av);
    RAWBAR; PRIO1; MF(1, av, bv); PRIO0; RAWBAR;
    // ph2: cvt+ds_write A-half0 (loads issued 2 phases ago)
    if (more) awrite(fa, nb, 0);
    rdB(B0, 1, bv); rdA(A0, 0, 1, av);
    RAWBAR; PRIO1; MF(0, av, bv); PRIO0; RAWBAR;
    // ph3: cvt+ds_write A-half1; boundary drain (B loads 2-3 phases old)
    if (more) awrite(fc, nb, 1);
    rdA(A0, 1, 1, av);
    RAWBAR; PRIO1; MF(1, av, bv); PRIO0;
    WAIT_VL; RAWBAR;
  }

  const float* b1e = b1 + (size_t)e * FF;
  float bias[4];
#pragma unroll
  for (int n = 0; n < 4; ++n) bias[n] = b1e[n0 + wc * 64 + n * 16 + lrow];
#pragma unroll
  for (int mi = 0; mi < 8; ++mi){
#pragma unroll
    for (int j = 0; j < 4; ++j){
      int row = row0 + wr * 128 + mi * 16 + lk * 4 + j;
      short* hr = h + (size_t)row * FF + n0 + wc * 64 + lrow;
#pragma unroll
      for (int n = 0; n < 4; ++n){
        float v = acc[mi][n][j] + bias[n];
        float u = 0.7978845608028654f * (v + 0.044715f * v * v * v);
        float gl = v / (1.0f + __expf(-2.0f * u));
        hr[n * 16] = (short)f2bf(gl);
      }
    }
  }
}

// ---------------- GEMM2 (K-half per launch): y = / += Hs @ W2[e] (+b2) ----------------

__launch_bounds__(512, 2)
__global__ void k_gemm2(const short* __restrict__ hA, const short* __restrict__ w2t,
                        const float* __restrict__ b2, float* __restrict__ y,
                        const int* __restrict__ poff, int kbeg, int am){
  __shared__ short As[2][2][8192];
  __shared__ short Bs[2][2][8192];
  int lin = xcd_swz(blockIdx.x, MT * (DD / 256));
  int by = lin / MT, bx = lin % MT;
  int row0 = bx * 256;
  if (row0 >= poff[NE]) return;
  int e = 0;
  while (row0 >= poff[e + 1]) ++e;
  int n0 = by * 256;
  int tid = threadIdx.x;
  int wid = tid >> 6, lane = tid & 63;
  int wr = wid >> 2, wc = wid & 3;
  int lrow = lane & 15, lk = lane >> 4;

  const short* asrc[2]; const short* bsrc[2];
#pragma unroll
  for (int p = 0; p < 2; ++p){
    int L = p * 512 + tid;
    int r = L >> 3, cd = (L & 7) ^ (r & 7);
    asrc[p] = hA + (size_t)(row0 + r) * FF + kbeg + cd * 8;
    bsrc[p] = w2t + (size_t)e * DD * FF + (size_t)(n0 + r) * FF + kbeg + cd * 8;
  }

  f32x4 acc[8][4];
#pragma unroll
  for (int i = 0; i < 8; ++i)
#pragma unroll
    for (int j = 0; j < 4; ++j) acc[i][j] = (f32x4){0.f, 0.f, 0.f, 0.f};

  auto rdA = [&](const short* A0, int mq, int kk, short8_t* av){
#pragma unroll
    for (int m = 0; m < 4; ++m){
      int r = mq * 64 + m * 16 + lrow;
      av[m] = *(const short8_t*)(A0 + r * 64 + (((kk * 4 + lk) ^ (r & 7)) << 3));
    }
  };
  auto rdB = [&](const short* B0, int kk, short8_t* bv){
#pragma unroll
    for (int n = 0; n < 4; ++n){
      int r = (wc & 1) * 64 + n * 16 + lrow;
      bv[n] = *(const short8_t*)(B0 + r * 64 + (((kk * 4 + lk) ^ (r & 7)) << 3));
    }
  };
  auto MF = [&](int mq, short8_t* av, short8_t* bv){
#pragma unroll
    for (int m = 0; m < 4; ++m)
#pragma unroll
      for (int n = 0; n < 4; ++n)
        acc[mq * 4 + m][n] = __builtin_amdgcn_mfma_f32_16x16x32_bf16(av[m], bv[n], acc[mq * 4 + m][n], 0, 0, 0);
  };
  auto astage = [&](int nb, int h2, int k0){
    GLOAD_LDS(asrc[0] + (size_t)h2 * 128 * FF + k0, &As[nb][h2][0] + tid * 8);
    GLOAD_LDS(asrc[1] + (size_t)h2 * 128 * FF + k0, &As[nb][h2][0] + 4096 + tid * 8);
  };
  auto bstage = [&](int nb, int h2, int k0){
    GLOAD_LDS(bsrc[0] + (size_t)h2 * 128 * FF + k0, &Bs[nb][h2][0] + tid * 8);
    GLOAD_LDS(bsrc[1] + (size_t)h2 * 128 * FF + k0, &Bs[nb][h2][0] + 4096 + tid * 8);
  };

  astage(0, 0, 0); astage(0, 1, 0);
  bstage(0, 0, 0); bstage(0, 1, 0);
  WAIT_V; RAWBAR;

  const int NKT = 2048 / BK;   // 32
#pragma unroll 1
  for (int kt = 0; kt < NKT; ++kt){
    int buf = kt & 1, nb = buf ^ 1;
    int k1 = (kt + 1) * BK;
    bool more = (kt + 1 < NKT);
    const short* A0 = &As[buf][wr][0];
    const short* B0 = &Bs[buf][wc >> 1][0];
    short8_t av[4], bv[4];
    if (more){ astage(nb, 0, k1); bstage(nb, 0, k1); }
    rdB(B0, 0, bv); rdA(A0, 0, 0, av);
    RAWBAR; PRIO1; MF(0, av, bv); PRIO0; RAWBAR;
    if (more){ astage(nb, 1, k1); bstage(nb, 1, k1); }
    rdA(A0, 1, 0, av);
    RAWBAR; PRIO1; MF(1, av, bv); PRIO0; RAWBAR;
    rdB(B0, 1, bv); rdA(A0, 0, 1, av);
    RAWBAR; PRIO1; MF(0, av, bv); PRIO0; RAWBAR;
    rdA(A0, 1, 1, av);
    RAWBAR; PRIO1; MF(1, av, bv); PRIO0;
    WAIT_V; RAWBAR;
  }

  float bias[4];
  const float* b2e = b2 + (size_t)e * DD;
#pragma unroll
  for (int n = 0; n < 4; ++n) bias[n] = b2e[n0 + wc * 64 + n * 16 + lrow];
#pragma unroll
  for (int mi = 0; mi < 8; ++mi){
#pragma unroll
    for (int j = 0; j < 4; ++j){
      int row = row0 + wr * 128 + mi * 16 + lk * 4 + j;
      float* yr = y + (size_t)row * DD + n0 + wc * 64 + lrow;
      if (am){
#pragma unroll
        for (int n = 0; n < 4; ++n) yr[n * 16] += acc[mi][n][j];
      } else {
#pragma unroll
        for (int n = 0; n < 4; ++n) yr[n * 16] = acc[mi][n][j] + bias[n];
      }
    }
  }
}

// ---------------- combine: out[t] = g0*y[s0] + g1*y[s1] ----------------

__global__ void k_combine(const float* __restrict__ y, const int* __restrict__ slot_of,
                          const float* __restrict__ topk_gate, float* __restrict__ out){
  int i = blockIdx.x * 256 + threadIdx.x;
  int t = i >> 8;
  int c4 = (i & 255) * 4;
  int s0 = slot_of[2 * t], s1 = slot_of[2 * t + 1];
  float g0 = topk_gate[2 * t], g1 = topk_gate[2 * t + 1];
  float4 a = *(const float4*)(y + (size_t)s0 * DD + c4);
  float4 b = *(const float4*)(y + (size_t)s1 * DD + c4);
  float4 o;
  o.x = g0 * a.x + g1 * b.x;
  o.y = g0 * a.y + g1 * b.y;
  o.z = g0 * a.z + g1 * b.z;
  o.w = g0 * a.w + g1 * b.w;
  *(float4*)(out + (size_t)t * DD + c4) = o;
}

// ---------------- launch ----------------

extern "C" void kernel_launch(void* const* d_in, const int* in_sizes, int n_in,
                              void* d_out, int out_size, void* d_ws, size_t ws_size,
                              hipStream_t stream){
  (void)in_sizes; (void)n_in; (void)out_size; (void)ws_size;
  const float* x  = (const float*)d_in[0];
  const float* Wg = (const float*)d_in[1];
  const float* W1 = (const float*)d_in[2];
  const float* b1 = (const float*)d_in[3];
  const float* W2 = (const float*)d_in[4];
  const float* b2 = (const float*)d_in[5];
  float* out = (float*)d_out;
  char* ws = (char*)d_ws;

  int*   counts    = (int*)(ws + 0);
  int*   poff      = (int*)(ws + 64);
  int*   topk_idx  = (int*)(ws + 1024);            // 32768
  float* topk_gate = (float*)(ws + 33792);         // 32768
  int*   row_token = (int*)(ws + 66560);           // 40960
  int*   slot_of   = (int*)(ws + 107520);          // 32768 -> 140288
  short* w1t       = (short*)(ws + 143360);        // 67108864 -> 67252224
  short* w2t       = (short*)(ws + 67252224);      // 67108864 -> 134361088
  short* h         = (short*)(ws + 134361088);     // 83886080 -> 218247168
  float* ya        = (float*)(ws + 143360);        // 41943040, aliases w1t (dead at gemm2)

  hipMemsetAsync(counts, 0, 64, stream);

  k_prep<<<dim3(NTOK / 4), 256, 0, stream>>>(x, Wg, topk_idx, topk_gate, counts);
  k_transpose_all<<<dim3(8192), 256, 0, stream>>>(W1, W2, w1t, w2t);
  k_route_all<<<dim3(1), 256, 0, stream>>>(counts, topk_idx, topk_gate, poff,
                                           row_token, slot_of);
  k_gemm1<<<dim3(MT * (FF / 256)), 512, 0, stream>>>(x, w1t, b1, h, row_token, poff);
  k_gemm2<<<dim3(MT * (DD / 256)), 512, 0, stream>>>(h, w2t, b2, ya, poff, 0, 0);
  k_gemm2<<<dim3(MT * (DD / 256)), 512, 0, stream>>>(h, w2t, b2, ya, poff, 2048, 1);
  k_combine<<<dim3(NTOK * DD / 4 / 256), 256, 0, stream>>>(ya, slot_of, topk_gate, out);
}